// Round 18
// baseline (1189.320 us; speedup 1.0000x reference)
//
#include <hip/hip_runtime.h>
#include <hip/hip_bf16.h>

// SwiGLU MLP: out = down( silu(x@Wg^T + bg) * (x@Wu^T + bu) ) + bd
// M=4096 tokens, H=4096, I=11008. fp32 in/out, bf16 MFMA compute.
// R18 = R17 (32x32x16 MFMA, fragment layouts HW-verified by R17's absmax pass)
// with a NEW conflict-free LDS layout: each 32-row x 16-k fragment-pair block is
// a LINEAR 1024B run (lane l's 16B at (l31&15)*64 + ((l31>>4)&1)*32 + hi*16 —
// bijection onto the block => every ds_read_b128 is a contiguous aligned 1024B
// wave read => zero bank conflicts by construction, R8-verified mechanism).
// global_load_lds dest stays linear; the gather moved to the per-lane global
// source decode (adjacent lanes cover 64B lines => coalesced).
// Sync skeleton, counted vmcnt(6)/(2), cvt3, wd tail-fill: R16-verbatim.

#define M_TOK 4096
#define HID   4096
#define INT_  11008
#define NGU   1376          // 16 * 86 gu tiles (%8==0)
#define NCVT  128           // wd-convert tail blocks

typedef __attribute__((ext_vector_type(8))) short bf16x8;
typedef __attribute__((ext_vector_type(4))) float f32x4;
typedef __attribute__((ext_vector_type(16))) float f32x16;

__device__ __forceinline__ unsigned short f2bf(float f) {
    union { float f; unsigned int u; } a; a.f = f;
    unsigned int u = a.u;
    u += 0x7fff + ((u >> 16) & 1);   // RNE
    return (unsigned short)(u >> 16);
}

// ---------------- combined fp32 -> bf16 convert: x, wg, wu in one launch -------
__global__ void cvt3(const float* __restrict__ x,  unsigned short* __restrict__ xb,
                     const float* __restrict__ wg, unsigned short* __restrict__ s1,
                     const float* __restrict__ wu, unsigned short* __restrict__ s2,
                     int n4x, int n4w) {
    const int total = n4x + 2 * n4w;
    const int stride = gridDim.x * blockDim.x;
    for (int i = blockIdx.x * blockDim.x + threadIdx.x; i < total; i += stride) {
        const float* src; unsigned short* dst; int j;
        if (i < n4x)            { j = i;             src = x;  dst = xb; }
        else if (i < n4x + n4w) { j = i - n4x;       src = wg; dst = s1; }
        else                    { j = i - n4x - n4w; src = wu; dst = s2; }
        float4 v = ((const float4*)src)[j];
        ushort4 o;
        o.x = f2bf(v.x); o.y = f2bf(v.y); o.z = f2bf(v.z); o.w = f2bf(v.w);
        ((ushort4*)dst)[j] = o;
    }
}

// ---------------- standalone fp32 -> bf16 (fallback path for wd) ---------------
__global__ void cvt_f32_bf16(const float* __restrict__ in, unsigned short* __restrict__ out, int n4) {
    int stride = gridDim.x * blockDim.x;
    for (int i = blockIdx.x * blockDim.x + threadIdx.x; i < n4; i += stride) {
        float4 v = ((const float4*)in)[i];
        ushort4 o;
        o.x = f2bf(v.x); o.y = f2bf(v.y); o.z = f2bf(v.z); o.w = f2bf(v.w);
        ((ushort4*)out)[i] = o;
    }
}

#define GLL(gsrc, ldst) \
    __builtin_amdgcn_global_load_lds( \
        (__attribute__((address_space(1))) void*)(gsrc), \
        (__attribute__((address_space(3))) void*)(ldst), 16, 0, 0)

#define VMC(n) asm volatile("s_waitcnt vmcnt(" #n ")" ::: "memory")
#define BARR __builtin_amdgcn_s_barrier()
#define PIN  __builtin_amdgcn_sched_barrier(0)

#define ZERO16(V) { _Pragma("unroll") for (int z_ = 0; z_ < 16; ++z_) V[z_] = 0.f; }

// LDS region layout per K-tile buffer (shorts), BK=64:
//  A  [0,16384): 256 rows. 8 blocks of (32 rows x 16 k) = 512 shorts each.
//     block(row>>5 = wm*4+mb) at phys: (mb>>1)*8192 + wm*4096 + (mb&1)*2048,
//     + kk*512 within; lane chunk: (row&15)*32 + ((row>>4)&1)*16 + oct*8.
//  gu: Bg [16384,24576): 4 blocks (col>>5 = wn) at 16384 + wn*2048.
//      Bu [24576,32768): same at 24576.
//  dn: B  [16384,32768): 8 blocks (col>>5 = qn*4+wn) at 16384 + b*2048.

// ================= FUSED gate+up (+ wd-convert tail blocks) ====================
__global__ __launch_bounds__(512, 2)
void gemm_gu(const unsigned short* __restrict__ A,
             const unsigned short* __restrict__ Wg,
             const unsigned short* __restrict__ Wu,
             const float* __restrict__ bg,
             const float* __restrict__ bu,
             unsigned short* __restrict__ T,
             const float* __restrict__ wdSrc,
             unsigned short* __restrict__ wdDst,
             int M, int NI, int K) {
    __shared__ unsigned short lds[2 * 32768];   // 128 KiB

    const int tid  = threadIdx.x;

    // ---- wd-convert tail blocks (dispatched last -> fill gu's ragged round) ----
    if (blockIdx.x >= NGU) {
        const int c = blockIdx.x - NGU;            // 0..127
        const size_t base = (size_t)c * 88064;     // float4 units; 128*88064*4 == I*H
        const float4* src = (const float4*)wdSrc + base;
        ushort4* dst = (ushort4*)wdDst + base;
#pragma unroll 4
        for (int it = 0; it < 172; ++it) {         // 172*512 == 88064
            const int u = it * 512 + tid;
            float4 v = src[u];
            ushort4 o;
            o.x = f2bf(v.x); o.y = f2bf(v.y); o.z = f2bf(v.z); o.w = f2bf(v.w);
            dst[u] = o;
        }
        return;
    }

    const int lane = tid & 63;
    const int w    = tid >> 6;
    const int wm   = w >> 2;         // 0..1  (128 rows)
    const int wn   = w & 3;          // 0..3  (32 inter-cols)

    // XCD-aware bijective swizzle over the NGU gemm blocks (NGU % 8 == 0)
    const int ntn = NI >> 7;                    // 86
    const int chunk = NGU >> 3;                 // 172
    const int sw = (blockIdx.x & 7) * chunk + (blockIdx.x >> 3);
    const int bm = sw / ntn, bn = sw % ntn;

    const unsigned short* Ag  = A  + (size_t)(bm * 256) * K;
    const unsigned short* Bgg = Wg + (size_t)(bn * 128) * K;
    const unsigned short* Bug = Wu + (size_t)(bn * 128) * K;

    // ---- staging source decode (LDS dest linear: tid*16B per GLL) ----
    int gOffA[2][2], gOffW[2];
#pragma unroll
    for (int h = 0; h < 2; ++h)
#pragma unroll
        for (int g = 0; g < 2; ++g) {
            int c   = g * 512 + tid;
            int wmD = c >> 9, j = (c >> 8) & 1;
            int kk  = (c >> 6) & 3;
            int q   = (c >> 2) & 15, hh = (c >> 1) & 1, o = c & 1;
            int row = wmD * 128 + (h * 2 + j) * 32 + hh * 16 + q;
            int k   = kk * 16 + o * 8;
            gOffA[h][g] = row * K + k;
            if (h == 0) {
                int colB = ((c >> 8) & 3) * 32 + hh * 16 + q;
                gOffW[g] = colB * K + k;
            }
        }

    // ---- fragment read lane offset (linear block layout) ----
    const int l31 = lane & 31;
    const int hi  = lane >> 5;
    const int aLane = (l31 & 15) * 32 + ((l31 >> 4) & 1) * 16 + hi * 8;

    f32x16 accg[4], accu[4];          // mb 0..3 (32-row blocks of wm's 128)
#pragma unroll
    for (int mb = 0; mb < 4; ++mb) { ZERO16(accg[mb]); ZERO16(accu[mb]); }

    const int NT = K >> 6;

#define STAGE_A(H, DST, SRC) \
    GLL((SRC) + gOffA[H][0], (DST) + (H) * 8192 + tid * 8); \
    GLL((SRC) + gOffA[H][1], (DST) + (H) * 8192 + 4096 + tid * 8)
#define STAGE_W(BASE, DST, SRC) \
    GLL((SRC) + gOffW[0], (DST) + (BASE) + tid * 8); \
    GLL((SRC) + gOffW[1], (DST) + (BASE) + 4096 + tid * 8)

#define RD_A32(BUF, HALF, DST) \
    { _Pragma("unroll") for (int mb2 = 0; mb2 < 2; ++mb2) \
      _Pragma("unroll") for (int kk = 0; kk < 4; ++kk) \
        DST[mb2 * 4 + kk] = *(const bf16x8*)((BUF) + (HALF) * 8192 + wm * 4096 + mb2 * 2048 + kk * 512 + aLane); }
#define RD_W32(BUF, BASE, DST) \
    { _Pragma("unroll") for (int kk = 0; kk < 4; ++kk) \
        DST[kk] = *(const bf16x8*)((BUF) + (BASE) + wn * 2048 + kk * 512 + aLane); }
#define Q8(ACC, MB0, AF, BF) \
    { _Pragma("unroll") for (int mb2 = 0; mb2 < 2; ++mb2) \
      _Pragma("unroll") for (int kk = 0; kk < 4; ++kk) \
        ACC[(MB0) + mb2] = __builtin_amdgcn_mfma_f32_32x32x16_bf16( \
            AF[mb2 * 4 + kk], BF[kk], ACC[(MB0) + mb2], 0, 0, 0); }

    bf16x8 A0f[8], A1f[8], Bgf[4], Buf_[4];

    // prologue: stage tile 0 as A0,Bg,Bu,A1; invariant: only A1 in flight
    STAGE_A(0, lds, Ag);
    STAGE_W(16384, lds, Bgg);
    STAGE_W(24576, lds, Bug);
    STAGE_A(1, lds, Ag);
    VMC(2);
    BARR; PIN;

    for (int t = 0; t < NT; ++t) {
        const unsigned short* bc = lds + (t & 1) * 32768;
        unsigned short* sb = lds + ((t + 1) & 1) * 32768;
        const int ts = (t + 1 < NT) ? (t + 1) : (NT - 1);
        const unsigned short* sA = Ag + (size_t)ts * 64;
        const unsigned short* sG = Bgg + (size_t)ts * 64;
        const unsigned short* sU = Bug + (size_t)ts * 64;

        // chunk1: A-half0 (mb 0,1); 16 MFMA; stage A0,Bg,Bu(t+1)
        RD_A32(bc, 0, A0f);
        RD_W32(bc, 16384, Bgf);
        STAGE_A(0, sb, sA);
        Q8(accg, 0, A0f, Bgf);
        RD_W32(bc, 24576, Buf_);
        STAGE_W(16384, sb, sG);
        Q8(accu, 0, A0f, Buf_);
        STAGE_W(24576, sb, sU);
        VMC(6);                         // retires t.A1
        BARR; PIN;

        // chunk2: A-half1 (mb 2,3); 16 MFMA; stage A1(t+1)
        RD_A32(bc, 1, A1f);
        STAGE_A(1, sb, sA);
        Q8(accg, 2, A1f, Bgf);
        Q8(accu, 2, A1f, Buf_);
        VMC(2);                         // retires t+1.A0,Bg,Bu
        BARR; PIN;
    }
#undef RD_A32
#undef RD_W32
#undef Q8
#undef STAGE_A
#undef STAGE_W

    // epilogue: col=lane&31; row=(reg&3)+8*(reg>>2)+4*hi  [m101/R17-verified]
    const int rowW = bm * 256 + wm * 128;
    const int col  = bn * 128 + wn * 32 + l31;
    const float bgv = bg[col];
    const float buv = bu[col];
#pragma unroll
    for (int mb = 0; mb < 4; ++mb) {
#pragma unroll
        for (int reg = 0; reg < 16; ++reg) {
            const int row = rowW + mb * 32 + (reg & 3) + ((reg >> 2) << 3) + (hi << 2);
            float g = accg[mb][reg] + bgv;
            float u = accu[mb][reg] + buv;
            float s = g / (1.f + __expf(-g)) * u;
            T[(size_t)row * (size_t)INT_ + col] = f2bf(s);
        }
    }
}

// ================= down GEMM: out = t @ Wd^T + bd (fp32), 32x32x16 =============
__global__ __launch_bounds__(512, 2)
void gemm_dn(const unsigned short* __restrict__ A,
             const unsigned short* __restrict__ B,
             const float* __restrict__ bias,
             float* __restrict__ C,
             int M, int N, int K) {
    __shared__ unsigned short lds[2 * 32768];   // 128 KiB

    const int tid  = threadIdx.x;
    const int lane = tid & 63;
    const int w    = tid >> 6;
    const int wm   = w >> 2;
    const int wn   = w & 3;

    const int ntn = N >> 8;
    const int chunk = gridDim.x >> 3;
    const int sw = (blockIdx.x & 7) * chunk + (blockIdx.x >> 3);
    const int bm = sw / ntn, bn = sw % ntn;

    const unsigned short* Ag = A + (size_t)(bm * 256) * K;
    const unsigned short* Bg = B + (size_t)(bn * 256) * K;

    // staging source decode
    int gOffA[2][2], gOffB[2][2];
#pragma unroll
    for (int h = 0; h < 2; ++h)
#pragma unroll
        for (int g = 0; g < 2; ++g) {
            int c   = g * 512 + tid;
            int wmD = c >> 9, j = (c >> 8) & 1;
            int kk  = (c >> 6) & 3;
            int q   = (c >> 2) & 15, hh = (c >> 1) & 1, o = c & 1;
            int row = wmD * 128 + (h * 2 + j) * 32 + hh * 16 + q;
            int k   = kk * 16 + o * 8;
            gOffA[h][g] = row * K + k;
            int colB = (h * 4 + ((c >> 8) & 3)) * 32 + hh * 16 + q;
            gOffB[h][g] = colB * K + k;
        }

    const int l31 = lane & 31;
    const int hi  = lane >> 5;
    const int aLane = (l31 & 15) * 32 + ((l31 >> 4) & 1) * 16 + hi * 8;

    f32x16 acc[4][2];                 // [mb][qn]
#pragma unroll
    for (int mb = 0; mb < 4; ++mb) { ZERO16(acc[mb][0]); ZERO16(acc[mb][1]); }

    const int NT = K >> 6;

#define STAGE_A(H, DST, SRC) \
    GLL((SRC) + gOffA[H][0], (DST) + (H) * 8192 + tid * 8); \
    GLL((SRC) + gOffA[H][1], (DST) + (H) * 8192 + 4096 + tid * 8)
#define STAGE_B(H, DST, SRC) \
    GLL((SRC) + gOffB[H][0], (DST) + 16384 + (H) * 8192 + tid * 8); \
    GLL((SRC) + gOffB[H][1], (DST) + 16384 + (H) * 8192 + 4096 + tid * 8)
#define RD_A32(BUF, HALF, DST) \
    { _Pragma("unroll") for (int mb2 = 0; mb2 < 2; ++mb2) \
      _Pragma("unroll") for (int kk = 0; kk < 4; ++kk) \
        DST[mb2 * 4 + kk] = *(const bf16x8*)((BUF) + (HALF) * 8192 + wm * 4096 + mb2 * 2048 + kk * 512 + aLane); }
#define RD_B32(BUF, QN, DST) \
    { _Pragma("unroll") for (int kk = 0; kk < 4; ++kk) \
        DST[kk] = *(const bf16x8*)((BUF) + 16384 + ((QN) * 4 + wn) * 2048 + kk * 512 + aLane); }
#define Q8D(MB0, QN, AF, BF) \
    { _Pragma("unroll") for (int mb2 = 0; mb2 < 2; ++mb2) \
      _Pragma("unroll") for (int kk = 0; kk < 4; ++kk) \
        acc[(MB0) + mb2][QN] = __builtin_amdgcn_mfma_f32_32x32x16_bf16( \
            AF[mb2 * 4 + kk], BF[kk], acc[(MB0) + mb2][QN], 0, 0, 0); }

    bf16x8 A0f[8], A1f[8], B0f[4], B1f[4];

    STAGE_A(0, lds, Ag); STAGE_B(0, lds, Bg); STAGE_B(1, lds, Bg); STAGE_A(1, lds, Ag);
    VMC(2);
    BARR; PIN;

    for (int t = 0; t < NT; ++t) {
        const unsigned short* bc = lds + (t & 1) * 32768;
        unsigned short* sb = lds + ((t + 1) & 1) * 32768;
        const int ts = (t + 1 < NT) ? (t + 1) : (NT - 1);
        const unsigned short* sAt = Ag + (size_t)ts * 64;
        const unsigned short* sBt = Bg + (size_t)ts * 64;

        // chunk1: A-half0 (mb 0,1); 16 MFMA; stage A0,B0,B1(t+1)
        RD_A32(bc, 0, A0f);
        RD_B32(bc, 0, B0f);
        STAGE_A(0, sb, sAt);
        Q8D(0, 0, A0f, B0f);
        RD_B32(bc, 1, B1f);
        STAGE_B(0, sb, sBt);
        Q8D(0, 1, A0f, B1f);
        STAGE_B(1, sb, sBt);
        VMC(6);
        BARR; PIN;

        // chunk2: A-half1 (mb 2,3); 16 MFMA; stage A1(t+1)
        RD_A32(bc, 1, A1f);
        STAGE_A(1, sb, sAt);
        Q8D(2, 1, A1f, B1f);
        Q8D(2, 0, A1f, B0f);
        VMC(2);
        BARR; PIN;
    }
#undef RD_A32
#undef RD_B32
#undef Q8D
#undef STAGE_A
#undef STAGE_B

    const int rowW = bm * 256 + wm * 128;
#pragma unroll
    for (int mb = 0; mb < 4; ++mb)
#pragma unroll
        for (int qn = 0; qn < 2; ++qn) {
            const int col = bn * 256 + qn * 128 + wn * 32 + l31;
            const float bv = bias[col];
#pragma unroll
            for (int reg = 0; reg < 16; ++reg) {
                const int row = rowW + mb * 32 + (reg & 3) + ((reg >> 2) << 3) + (hi << 2);
                C[(size_t)row * (size_t)N + col] = acc[mb][qn][reg] + bv;
            }
        }
}

// ---------------- launcher ----------------
extern "C" void kernel_launch(void* const* d_in, const int* in_sizes, int n_in,
                              void* d_out, int out_size, void* d_ws, size_t ws_size,
                              hipStream_t stream) {
    const float* x  = (const float*)d_in[0];   // (2,2048,4096)
    const float* wg = (const float*)d_in[1];   // (11008,4096)
    const float* bg = (const float*)d_in[2];
    const float* wu = (const float*)d_in[3];
    const float* bu = (const float*)d_in[4];
    const float* wd = (const float*)d_in[5];   // (4096,11008)
    const float* bd = (const float*)d_in[6];

    const size_t NX = (size_t)M_TOK * HID;     // 16,777,216
    const size_t NW = (size_t)INT_ * HID;      // 45,088,768

    unsigned short* ws = (unsigned short*)d_ws;
    unsigned short* Xb = ws;                   // x bf16
    unsigned short* S1 = Xb + NX;              // Wg bf16 (fallback: -> Wd later)
    unsigned short* S2 = S1 + NW;              // Wu bf16
    unsigned short* S3 = S2 + NW;              // t = silu(g)*u bf16
    unsigned short* S4 = S3 + NW;              // Wd bf16 (fused path only)

    const bool fused = ws_size >= (NX + 4 * NW) * 2;   // 394,264,576 B

    dim3 blk512(512);
    dim3 blk256(256);

    cvt3<<<2048, blk256, 0, stream>>>(x, Xb, wg, S1, wu, S2,
                                      (int)(NX / 4), (int)(NW / 4));

    if (fused) {
        gemm_gu<<<dim3(NGU + NCVT), blk512, 0, stream>>>(Xb, S1, S2, bg, bu, S3,
                                                         wd, S4, M_TOK, INT_, HID);
        gemm_dn<<<dim3(16 * 16), blk512, 0, stream>>>(S3, S4, bd, (float*)d_out,
                                                      M_TOK, HID, INT_);
    } else {
        gemm_gu<<<dim3(NGU), blk512, 0, stream>>>(Xb, S1, S2, bg, bu, S3,
                                                  (const float*)nullptr,
                                                  (unsigned short*)nullptr,
                                                  M_TOK, INT_, HID);
        cvt_f32_bf16<<<2048, blk256, 0, stream>>>(wd, S1, (int)(NW / 4));
        gemm_dn<<<dim3(16 * 16), blk512, 0, stream>>>(S3, S1, bd, (float*)d_out,
                                                      M_TOK, HID, INT_);
    }
}

// Round 19
// 993.651 us; speedup vs baseline: 1.1969x; 1.1969x over previous
//
#include <hip/hip_runtime.h>
#include <hip/hip_bf16.h>

// SwiGLU MLP: out = down( silu(x@Wg^T + bg) * (x@Wu^T + bu) ) + bd
// M=4096 tokens, H=4096, I=11008. fp32 in/out, bf16 MFMA compute.
// R19 = R16 (best measured: 997us; 16x16x32 MFMA, XOR slot-swizzle w/ measured-0
// conflicts, semi-drift 2-sync/tile, counted vmcnt, fused gate+up, wd-convert
// tail fill, cvt3) with NCVT 128->160 (grid-stride) so gu's last dispatch round
// is exactly 512/512 slots (352 gemm + 160 cvt). 32x32x16 shape reverted —
// falsified twice (R17/R18: dependency-chain stalls, MfmaUtil 50/43 vs 56).

#define M_TOK 4096
#define HID   4096
#define INT_  11008
#define NGU   1376          // 16 * 86 gu tiles (%8==0)
#define NCVT  160           // wd-convert tail blocks (352+160 = 512 exact fill)

typedef __attribute__((ext_vector_type(8))) short bf16x8;
typedef __attribute__((ext_vector_type(4))) float f32x4;

__device__ __forceinline__ unsigned short f2bf(float f) {
    union { float f; unsigned int u; } a; a.f = f;
    unsigned int u = a.u;
    u += 0x7fff + ((u >> 16) & 1);   // RNE
    return (unsigned short)(u >> 16);
}

// ---------------- combined fp32 -> bf16 convert: x, wg, wu in one launch -------
__global__ void cvt3(const float* __restrict__ x,  unsigned short* __restrict__ xb,
                     const float* __restrict__ wg, unsigned short* __restrict__ s1,
                     const float* __restrict__ wu, unsigned short* __restrict__ s2,
                     int n4x, int n4w) {
    const int total = n4x + 2 * n4w;
    const int stride = gridDim.x * blockDim.x;
    for (int i = blockIdx.x * blockDim.x + threadIdx.x; i < total; i += stride) {
        const float* src; unsigned short* dst; int j;
        if (i < n4x)            { j = i;             src = x;  dst = xb; }
        else if (i < n4x + n4w) { j = i - n4x;       src = wg; dst = s1; }
        else                    { j = i - n4x - n4w; src = wu; dst = s2; }
        float4 v = ((const float4*)src)[j];
        ushort4 o;
        o.x = f2bf(v.x); o.y = f2bf(v.y); o.z = f2bf(v.z); o.w = f2bf(v.w);
        ((ushort4*)dst)[j] = o;
    }
}

// ---------------- standalone fp32 -> bf16 (fallback path for wd) ---------------
__global__ void cvt_f32_bf16(const float* __restrict__ in, unsigned short* __restrict__ out, int n4) {
    int stride = gridDim.x * blockDim.x;
    for (int i = blockIdx.x * blockDim.x + threadIdx.x; i < n4; i += stride) {
        float4 v = ((const float4*)in)[i];
        ushort4 o;
        o.x = f2bf(v.x); o.y = f2bf(v.y); o.z = f2bf(v.z); o.w = f2bf(v.w);
        ((ushort4*)out)[i] = o;
    }
}

#define GLL(gsrc, ldst) \
    __builtin_amdgcn_global_load_lds( \
        (__attribute__((address_space(1))) void*)(gsrc), \
        (__attribute__((address_space(3))) void*)(ldst), 16, 0, 0)

#define VMC(n) asm volatile("s_waitcnt vmcnt(" #n ")" ::: "memory")
#define BARR __builtin_amdgcn_s_barrier()
#define PIN  __builtin_amdgcn_sched_barrier(0)

// ================= FUSED gate+up (+ wd-convert tail blocks) ====================
// x: M x K bf16 row-major; Wg,Wu: I x K bf16 row-major; out t: M x I bf16.
// Blocks [0,NGU): GEMM tile 256(M) x 128(I), BK=64, 8 waves (2Mx4N), 16x16x32.
// Blocks [NGU, NGU+NCVT): convert wd fp32->bf16 (grid-stride with guard).
// LDS/buffer (shorts): A-half0 [0,8192) A-half1 [8192,16384)
//                      Bg [16384,24576)  Bu [24576,32768).  dbuf = 128 KiB.
// Within a row, 16B slot s stored at s^(r&7) (0 bank conflicts, R9-verified).
__global__ __launch_bounds__(512, 2)
void gemm_gu(const unsigned short* __restrict__ A,
             const unsigned short* __restrict__ Wg,
             const unsigned short* __restrict__ Wu,
             const float* __restrict__ bg,
             const float* __restrict__ bu,
             unsigned short* __restrict__ T,
             const float* __restrict__ wdSrc,      // fp32 wd (tail blocks)
             unsigned short* __restrict__ wdDst,   // bf16 wd out (tail blocks)
             int M, int NI, int K) {
    __shared__ unsigned short lds[2 * 32768];   // 128 KiB

    const int tid  = threadIdx.x;

    // ---- wd-convert tail blocks (dispatched last -> fill gu's ragged round) ----
    if (blockIdx.x >= NGU) {
        const int c = blockIdx.x - NGU;            // 0..NCVT-1
        const int n4w = (INT_ * HID) / 4;          // 11,272,192 float4 units
        const float4* src = (const float4*)wdSrc;
        ushort4* dst = (ushort4*)wdDst;
        for (int u = c * 512 + tid; u < n4w; u += NCVT * 512) {
            float4 v = src[u];
            ushort4 o;
            o.x = f2bf(v.x); o.y = f2bf(v.y); o.z = f2bf(v.z); o.w = f2bf(v.w);
            dst[u] = o;
        }
        return;
    }

    const int lane = tid & 63;
    const int w    = tid >> 6;
    const int wm   = w >> 2;         // 0..1  (128 rows)
    const int wn   = w & 3;          // 0..3  (32 inter-cols)

    // XCD-aware bijective swizzle over the NGU gemm blocks (NGU % 8 == 0)
    const int ntn = NI >> 7;                    // 86
    const int chunk = NGU >> 3;                 // 172
    const int sw = (blockIdx.x & 7) * chunk + (blockIdx.x >> 3);
    const int bm = sw / ntn, bn = sw % ntn;

    const unsigned short* Ag  = A  + (size_t)(bm * 256) * K;
    const unsigned short* Bgg = Wg + (size_t)(bn * 128) * K;
    const unsigned short* Bug = Wu + (size_t)(bn * 128) * K;

    // staging source offsets (pre-swizzled; LDS dest linear)
    int offA[2][2], offBW[2];
#pragma unroll
    for (int i = 0; i < 2; ++i) {
        int sig = i * 512 + tid;
        int r   = sig >> 3;            // packed row 0..127
        int s   = (sig & 7) ^ (r & 7); // logical 16B slot
#pragma unroll
        for (int h = 0; h < 2; ++h) {
            int grow = ((r >> 6) * 2 + h) * 64 + (r & 63);
            offA[h][i] = grow * K + s * 8;
        }
        offBW[i] = r * K + s * 8;      // B rows map 1:1
    }

    // ds_read fragment addressing (swizzled slots)
    const int rl = lane & 15;
    const int kg = lane >> 4;
    const int x  = rl & 7;
    const int aRow  = (wm * 64 + rl) * 64;
    const int bGoff = 16384 + (wn * 32 + rl) * 64;
    const int bUoff = 24576 + (wn * 32 + rl) * 64;
    int slt[2];
#pragma unroll
    for (int ks = 0; ks < 2; ++ks) slt[ks] = ((ks * 4 + kg) ^ x) * 8;

    f32x4 accg[2][8], accu[2][8];     // [qm][fm*2+fn]
#pragma unroll
    for (int q = 0; q < 2; ++q)
#pragma unroll
        for (int f = 0; f < 8; ++f) {
            accg[q][f] = (f32x4){0.f, 0.f, 0.f, 0.f};
            accu[q][f] = (f32x4){0.f, 0.f, 0.f, 0.f};
        }

    const int NT = K >> 6;

#define STAGE_A(H, DST, SRC) \
    GLL((SRC) + offA[H][0], (DST) + (H) * 8192 + tid * 8); \
    GLL((SRC) + offA[H][1], (DST) + (H) * 8192 + 4096 + tid * 8)
#define STAGE_W(BASE, DST, SRC) \
    GLL((SRC) + offBW[0], (DST) + (BASE) + tid * 8); \
    GLL((SRC) + offBW[1], (DST) + (BASE) + 4096 + tid * 8)

#define RD_A(BUF, QM, DST) \
    { _Pragma("unroll") for (int ks = 0; ks < 2; ++ks) \
      _Pragma("unroll") for (int fm = 0; fm < 4; ++fm) \
        DST[ks * 4 + fm] = *(const bf16x8*)((BUF) + (QM) * 8192 + aRow + fm * 1024 + slt[ks]); }
#define RD_W(BUF, ROFF, DST) \
    { _Pragma("unroll") for (int ks = 0; ks < 2; ++ks) \
      _Pragma("unroll") for (int fn = 0; fn < 2; ++fn) \
        DST[ks * 2 + fn] = *(const bf16x8*)((BUF) + (ROFF) + fn * 1024 + slt[ks]); }
#define Q16(ACC, QM, AF, BF) \
    { _Pragma("unroll") for (int ks = 0; ks < 2; ++ks) \
      _Pragma("unroll") for (int fm = 0; fm < 4; ++fm) \
      _Pragma("unroll") for (int fn = 0; fn < 2; ++fn) \
        ACC[QM][fm * 2 + fn] = __builtin_amdgcn_mfma_f32_16x16x32_bf16( \
            AF[ks * 4 + fm], BF[ks * 2 + fn], ACC[QM][fm * 2 + fn], 0, 0, 0); }

    bf16x8 A0f[8], A1f[8], Bgf[4], Buf_[4];

    // prologue: stage tile 0 as A0,Bg,Bu,A1; invariant: only A1 in flight
    STAGE_A(0, lds, Ag);
    STAGE_W(16384, lds, Bgg);
    STAGE_W(24576, lds, Bug);
    STAGE_A(1, lds, Ag);
    VMC(2);
    BARR; PIN;

    for (int t = 0; t < NT; ++t) {
        const unsigned short* bc = lds + (t & 1) * 32768;
        unsigned short* sb = lds + ((t + 1) & 1) * 32768;
        const int ts = (t + 1 < NT) ? (t + 1) : (NT - 1);
        const unsigned short* sA = Ag + (size_t)ts * 64;
        const unsigned short* sG = Bgg + (size_t)ts * 64;
        const unsigned short* sU = Bug + (size_t)ts * 64;

        // chunk1: A0,Bg,Bu proven; 32 MFMA; stage A0,Bg,Bu(t+1)
        RD_A(bc, 0, A0f);
        RD_W(bc, bGoff, Bgf);
        STAGE_A(0, sb, sA);
        Q16(accg, 0, A0f, Bgf);
        RD_W(bc, bUoff, Buf_);
        STAGE_W(16384, sb, sG);
        Q16(accu, 0, A0f, Buf_);
        STAGE_W(24576, sb, sU);
        VMC(6);                         // retires t.A1
        BARR; PIN;

        // chunk2: A1 proven; 32 MFMA; stage A1(t+1)
        RD_A(bc, 1, A1f);
        STAGE_A(1, sb, sA);
        Q16(accg, 1, A1f, Bgf);
        Q16(accu, 1, A1f, Buf_);
        VMC(2);                         // retires t+1.A0,Bg,Bu
        BARR; PIN;
    }
#undef RD_A
#undef RD_W
#undef Q16
#undef STAGE_A
#undef STAGE_W

    // epilogue: C/D layout col=lane&15, row=(lane>>4)*4+j; t = silu(g)*u -> bf16
    const int rbase = bm * 256 + wm * 128 + (lane >> 4) * 4;
    const int cbase = bn * 128 + wn * 32 + (lane & 15);
#pragma unroll
    for (int qm = 0; qm < 2; ++qm)
#pragma unroll
        for (int fn = 0; fn < 2; ++fn) {
            const int col = cbase + fn * 16;
            const float bgv = bg[col];
            const float buv = bu[col];
#pragma unroll
            for (int fm = 0; fm < 4; ++fm) {
                const int rb = rbase + qm * 64 + fm * 16;
#pragma unroll
                for (int j = 0; j < 4; ++j) {
                    float g = accg[qm][fm * 2 + fn][j] + bgv;
                    float u = accu[qm][fm * 2 + fn][j] + buv;
                    float s = g / (1.f + __expf(-g)) * u;
                    T[(size_t)(rb + j) * (size_t)INT_ + col] = f2bf(s);
                }
            }
        }
}

// ================= down GEMM (R11 verbatim, fp32 epilogue) ======================
__global__ __launch_bounds__(512, 2)
void gemm_dn(const unsigned short* __restrict__ A,
             const unsigned short* __restrict__ B,
             const float* __restrict__ bias,
             float* __restrict__ C,
             int M, int N, int K) {
    __shared__ unsigned short lds[2 * 32768];   // 128 KiB

    const int tid  = threadIdx.x;
    const int lane = tid & 63;
    const int w    = tid >> 6;
    const int wm   = w >> 2;
    const int wn   = w & 3;

    const int ntn = N >> 8;
    const int chunk = gridDim.x >> 3;
    const int sw = (blockIdx.x & 7) * chunk + (blockIdx.x >> 3);
    const int bm = sw / ntn, bn = sw % ntn;

    const unsigned short* Ag = A + (size_t)(bm * 256) * K;
    const unsigned short* Bg = B + (size_t)(bn * 256) * K;

    int offA[2][2], offB[2][2];
#pragma unroll
    for (int h = 0; h < 2; ++h)
#pragma unroll
        for (int i = 0; i < 2; ++i) {
            int sig = i * 512 + tid;
            int r   = sig >> 3;
            int s   = (sig & 7) ^ (r & 7);
            int grow = ((r >> 6) * 2 + h) * 64 + (r & 63);
            int gcol = ((r >> 5) * 2 + h) * 32 + (r & 31);
            offA[h][i] = grow * K + s * 8;
            offB[h][i] = gcol * K + s * 8;
        }

    const int rl = lane & 15;
    const int kg = lane >> 4;
    const int x  = rl & 7;
    const int aRow = (wm * 64 + rl) * 64;
    const int bRow = 16384 + (wn * 32 + rl) * 64;
    int slt[2];
#pragma unroll
    for (int ks = 0; ks < 2; ++ks) slt[ks] = ((ks * 4 + kg) ^ x) * 8;

    f32x4 acc[2][2][8];
#pragma unroll
    for (int qm = 0; qm < 2; ++qm)
#pragma unroll
        for (int qn = 0; qn < 2; ++qn)
#pragma unroll
            for (int f = 0; f < 8; ++f)
                acc[qm][qn][f] = (f32x4){0.f, 0.f, 0.f, 0.f};

    const int NT = K >> 6;

#define STAGE_A(H, DST, SRC) \
    GLL((SRC) + offA[H][0], (DST) + (H) * 8192 + tid * 8); \
    GLL((SRC) + offA[H][1], (DST) + (H) * 8192 + 4096 + tid * 8)
#define STAGE_B(H, DST, SRC) \
    GLL((SRC) + offB[H][0], (DST) + 16384 + (H) * 8192 + tid * 8); \
    GLL((SRC) + offB[H][1], (DST) + 16384 + (H) * 8192 + 4096 + tid * 8)
#define RD_A(BUF, QM, DST) \
    { _Pragma("unroll") for (int ks = 0; ks < 2; ++ks) \
      _Pragma("unroll") for (int fm = 0; fm < 4; ++fm) \
        DST[ks * 4 + fm] = *(const bf16x8*)((BUF) + (QM) * 8192 + aRow + fm * 1024 + slt[ks]); }
#define RD_B(BUF, QN, DST) \
    { _Pragma("unroll") for (int ks = 0; ks < 2; ++ks) \
      _Pragma("unroll") for (int fn = 0; fn < 2; ++fn) \
        DST[ks * 2 + fn] = *(const bf16x8*)((BUF) + (QN) * 8192 + bRow + fn * 1024 + slt[ks]); }
#define Q16(QM, QN, AF, BF) \
    { _Pragma("unroll") for (int ks = 0; ks < 2; ++ks) \
      _Pragma("unroll") for (int fm = 0; fm < 4; ++fm) \
      _Pragma("unroll") for (int fn = 0; fn < 2; ++fn) \
        acc[QM][QN][fm * 2 + fn] = __builtin_amdgcn_mfma_f32_16x16x32_bf16( \
            AF[ks * 4 + fm], BF[ks * 2 + fn], acc[QM][QN][fm * 2 + fn], 0, 0, 0); }

    bf16x8 A0f[8], A1f[8], B0f[4], B1f[4];

    STAGE_A(0, lds, Ag); STAGE_B(0, lds, Bg); STAGE_B(1, lds, Bg); STAGE_A(1, lds, Ag);
    VMC(2);
    BARR; PIN;

    for (int t = 0; t < NT; ++t) {
        const unsigned short* bc = lds + (t & 1) * 32768;
        unsigned short* sb = lds + ((t + 1) & 1) * 32768;
        const int ts = (t + 1 < NT) ? (t + 1) : (NT - 1);
        const unsigned short* sAt = Ag + (size_t)ts * 64;
        const unsigned short* sBt = Bg + (size_t)ts * 64;

        RD_A(bc, 0, A0f);
        RD_B(bc, 0, B0f);
        STAGE_A(0, sb, sAt);
        Q16(0, 0, A0f, B0f);
        RD_B(bc, 1, B1f);
        STAGE_B(0, sb, sBt);
        Q16(0, 1, A0f, B1f);
        STAGE_B(1, sb, sBt);
        VMC(6);
        BARR; PIN;

        RD_A(bc, 1, A1f);
        STAGE_A(1, sb, sAt);
        Q16(1, 1, A1f, B1f);
        Q16(1, 0, A1f, B0f);
        VMC(2);
        BARR; PIN;
    }
#undef RD_A
#undef RD_B
#undef Q16
#undef STAGE_A
#undef STAGE_B

    const int rbase = bm * 256 + wm * 128 + (lane >> 4) * 4;
    const int cbase = bn * 256 + wn * 64 + (lane & 15);
#pragma unroll
    for (int qm = 0; qm < 2; ++qm)
#pragma unroll
        for (int qn = 0; qn < 2; ++qn)
#pragma unroll
            for (int fn = 0; fn < 2; ++fn) {
                const int col = cbase + qn * 32 + fn * 16;
                const float bv = bias[col];
#pragma unroll
                for (int fm = 0; fm < 4; ++fm) {
                    const int rb = rbase + qm * 64 + fm * 16;
#pragma unroll
                    for (int j = 0; j < 4; ++j)
                        C[(size_t)(rb + j) * (size_t)N + col] = acc[qm][qn][fm * 2 + fn][j] + bv;
                }
            }
}

// ---------------- launcher ----------------
extern "C" void kernel_launch(void* const* d_in, const int* in_sizes, int n_in,
                              void* d_out, int out_size, void* d_ws, size_t ws_size,
                              hipStream_t stream) {
    const float* x  = (const float*)d_in[0];   // (2,2048,4096)
    const float* wg = (const float*)d_in[1];   // (11008,4096)
    const float* bg = (const float*)d_in[2];
    const float* wu = (const float*)d_in[3];
    const float* bu = (const float*)d_in[4];
    const float* wd = (const float*)d_in[5];   // (4096,11008)
    const float* bd = (const float*)d_in[6];

    const size_t NX = (size_t)M_TOK * HID;     // 16,777,216
    const size_t NW = (size_t)INT_ * HID;      // 45,088,768

    unsigned short* ws = (unsigned short*)d_ws;
    unsigned short* Xb = ws;                   // x bf16
    unsigned short* S1 = Xb + NX;              // Wg bf16 (fallback: -> Wd later)
    unsigned short* S2 = S1 + NW;              // Wu bf16
    unsigned short* S3 = S2 + NW;              // t = silu(g)*u bf16
    unsigned short* S4 = S3 + NW;              // Wd bf16 (fused path only)

    const bool fused = ws_size >= (NX + 4 * NW) * 2;   // 394,264,576 B

    dim3 blk512(512);
    dim3 blk256(256);

    cvt3<<<2048, blk256, 0, stream>>>(x, Xb, wg, S1, wu, S2,
                                      (int)(NX / 4), (int)(NW / 4));

    if (fused) {
        gemm_gu<<<dim3(NGU + NCVT), blk512, 0, stream>>>(Xb, S1, S2, bg, bu, S3,
                                                         wd, S4, M_TOK, INT_, HID);
        gemm_dn<<<dim3(16 * 16), blk512, 0, stream>>>(S3, S4, bd, (float*)d_out,
                                                      M_TOK, HID, INT_);
    } else {
        gemm_gu<<<dim3(NGU), blk512, 0, stream>>>(Xb, S1, S2, bg, bu, S3,
                                                  (const float*)nullptr,
                                                  (unsigned short*)nullptr,
                                                  M_TOK, INT_, HID);
        cvt_f32_bf16<<<2048, blk256, 0, stream>>>(wd, S1, (int)(NW / 4));
        gemm_dn<<<dim3(16 * 16), blk512, 0, stream>>>(S3, S1, bd, (float*)d_out,
                                                      M_TOK, HID, INT_);
    }
}